// Round 1
// baseline (105.382 us; speedup 1.0000x reference)
//
#include <hip/hip_runtime.h>

#define NDIM 80
#define NB (NDIM * NDIM)        // 6400 batches
#define MAT_ELEMS (NDIM * NDIM) // 6400 elements per batch matrix
#define LDM 81                  // padded leading dim: stride-81 words -> conflict-free
#define NUM_ITER 100
#define TOL 0.01f

// One block per batch. Build M = wr*rz + rc in LDS, run the whole power
// iteration from LDS. 320 threads = 4 threads per matrix row.
__global__ __launch_bounds__(320) void power_iter_kernel(
    const float* __restrict__ r_zeros,
    const float* __restrict__ r_const,
    const float* __restrict__ weights_r,
    float* __restrict__ V)
{
    __shared__ float M[NDIM * LDM];   // 25920 B
    __shared__ float v[NDIM];
    __shared__ float av[NDIM];
    __shared__ float red;

    const int t = threadIdx.x;
    const size_t base = (size_t)blockIdx.x * MAT_ELEMS;
    const float4* rz4 = reinterpret_cast<const float4*>(r_zeros + base);
    const float4* rc4 = reinterpret_cast<const float4*>(r_const + base);
    const float4* wr4 = reinterpret_cast<const float4*>(weights_r + base);

    // Stage M into LDS (row-major, padded). 1600 float4s, coalesced.
    for (int f = t; f < MAT_ELEMS / 4; f += 320) {
        float4 a = rz4[f];
        float4 c = rc4[f];
        float4 w = wr4[f];
        int e = f * 4;
        int i = e / NDIM;          // 80 % 4 == 0 -> a float4 never crosses a row
        int j = e - i * NDIM;
        float* dst = &M[i * LDM + j];
        dst[0] = fmaf(w.x, a.x, c.x);
        dst[1] = fmaf(w.y, a.y, c.y);
        dst[2] = fmaf(w.z, a.z, c.z);
        dst[3] = fmaf(w.w, a.w, c.w);
    }
    if (t < NDIM) v[t] = 0.11180339887498949f; // 1/sqrt(80)
    __syncthreads();

    const int r = t >> 2;   // row 0..79
    const int q = t & 3;    // column quarter

    // av = M * v  (4 threads per row, 20 cols each, combine via shfl_xor)
    auto matvec = [&]() {
        float p = 0.f;
        const float* Mr = &M[r * LDM + q * 20];
        const float* vq = &v[q * 20];
        #pragma unroll
        for (int k = 0; k < 20; ++k) p = fmaf(Mr[k], vq[k], p);
        p += __shfl_xor(p, 1);
        p += __shfl_xor(p, 2);
        if (q == 0) av[r] = p;
        __syncthreads();
    };

    // red = sum_i v[i]*av[i]   (wave 0 only; fixed order -> deterministic)
    auto reduce_dot = [&]() {
        if (t < 64) {
            float s = v[t] * av[t];
            if (t < 16) s += v[t + 64] * av[t + 64];
            #pragma unroll
            for (int o = 32; o > 0; o >>= 1) s += __shfl_down(s, o);
            if (t == 0) red = s;
        }
        __syncthreads();
    };

    matvec();       // av = M v0
    reduce_dot();   // ev0
    float ev = red;

    for (int it = 0; it < NUM_ITER; ++it) {
        __syncthreads();  // everyone has read `red`; safe to overwrite
        // nrm = ||av||
        if (t < 64) {
            float s = av[t] * av[t];
            if (t < 16) s += av[t + 64] * av[t + 64];
            #pragma unroll
            for (int o = 32; o > 0; o >>= 1) s += __shfl_down(s, o);
            if (t == 0) red = sqrtf(s);
        }
        __syncthreads();
        float nrm = red;
        if (t < NDIM) v[t] = av[t] / nrm;   // v_new
        __syncthreads();
        matvec();        // av = M v_new   (next step's Av, reused for ev_new)
        reduce_dot();    // ev_new = v_new . (M v_new)
        float evn = red;
        if (fabsf(ev - evn) < TOL) break;   // uniform across block
        ev = evn;
    }

    if (t < NDIM) V[(size_t)blockIdx.x * NDIM + t] = v[t];
}

// scale[b] = x[b]*wt[b]*r_const[i,j,i,i] / v[b][i],  b = i*80+j
__global__ void scale_kernel(const float* __restrict__ x,
                             const float* __restrict__ r_const,
                             const float* __restrict__ wt,
                             const float* __restrict__ V,
                             float* __restrict__ scale)
{
    int b = blockIdx.x * blockDim.x + threadIdx.x;
    if (b >= NB) return;
    int i = b / NDIM;
    float tval = x[b] * wt[b] * r_const[((size_t)b * NDIM + i) * NDIM + i];
    scale[b] = tval / V[(size_t)b * NDIM + i];
}

// out[k] = sum_b V[b][k] * scale[b]   (one block per k, fixed-order reduce)
__global__ __launch_bounds__(256) void out_kernel(
    const float* __restrict__ V,
    const float* __restrict__ scale,
    float* __restrict__ out)
{
    __shared__ float s[256];
    const int k = blockIdx.x;
    const int t = threadIdx.x;
    float acc = 0.f;
    for (int b = t; b < NB; b += 256)
        acc = fmaf(V[(size_t)b * NDIM + k], scale[b], acc);
    s[t] = acc;
    __syncthreads();
    for (int o = 128; o > 0; o >>= 1) {
        if (t < o) s[t] += s[t + o];
        __syncthreads();
    }
    if (t == 0) out[k] = s[0];
}

extern "C" void kernel_launch(void* const* d_in, const int* in_sizes, int n_in,
                              void* d_out, int out_size, void* d_ws, size_t ws_size,
                              hipStream_t stream) {
    const float* x  = (const float*)d_in[0];   // (80,80)
    const float* rz = (const float*)d_in[1];   // (80,80,80,80)
    const float* rc = (const float*)d_in[2];   // (80,80,80,80)
    const float* wt = (const float*)d_in[3];   // (80,80)
    const float* wr = (const float*)d_in[4];   // (80,80,80,80)
    float* out = (float*)d_out;                // (80,)

    float* V     = (float*)d_ws;               // 6400*80 floats
    float* scale = V + (size_t)NB * NDIM;      // 6400 floats

    hipLaunchKernelGGL(power_iter_kernel, dim3(NB), dim3(320), 0, stream,
                       rz, rc, wr, V);
    hipLaunchKernelGGL(scale_kernel, dim3((NB + 255) / 256), dim3(256), 0, stream,
                       x, rc, wt, V, scale);
    hipLaunchKernelGGL(out_kernel, dim3(NDIM), dim3(256), 0, stream,
                       V, scale, out);
}